// Round 4
// baseline (692.326 us; speedup 1.0000x reference)
//
#include <hip/hip_runtime.h>
#include <math.h>

#define NA 8192
#define NE 32768
#define NB 512                 // grid blocks; __launch_bounds__(256,2) => 2 blocks/CU co-resident
#define NT 256
#define JSPLIT 32
#define JCHUNK (NA / JSPLIT)   /* 256 j-atoms per steric tile */
#define NIB 16                 /* i-blocks: NA / (NT*2), ITILE=2 */

// ---- workspace layout (4-byte element offsets) ----
#define WS_DEG      0                      // int  NA
#define WS_LOSS     (WS_DEG + NA)          // f32  4
#define WS_BAR      (WS_LOSS + 4)          // int  2 (cnt, gen)
#define WS_ZERO_END (WS_BAR + 2)           // zero [0, WS_ZERO_END)
#define WS_POS2     8200                   // float4 NA (16B aligned: 8200*4 % 16 == 0)
#define WS_POS1A    (WS_POS2 + 4*NA)       // f32 3NA
#define WS_POS1     (WS_POS1A + 3*NA)      // f32 3NA
#define WS_VIOL     (WS_POS1 + 3*NA)       // f32 NA
#define WS_PART     (WS_VIOL + NA)         // float4 JSPLIT*NA  (4 MB) — 16B aligned
// total ws: (WS_PART + 4*JSPLIT*NA)*4 B ~= 4.6 MB

// ---- chemistry tables (types present: {1,6,7,8,9,15,16,17}) ----
__device__ __forceinline__ float maxval_of(int z) {
    switch (z) {
        case 1: return 1.f; case 6: return 4.f; case 7: return 3.f; case 8: return 2.f;
        case 9: return 1.f; case 15: return 5.f; case 16: return 6.f; case 17: return 1.f;
        case 35: return 1.f; case 53: return 1.f; default: return 4.f;
    }
}
__device__ __forceinline__ float vdw_of(int z) {
    switch (z) {
        case 1: return 1.2f; case 6: return 1.7f; case 7: return 1.55f; case 8: return 1.52f;
        case 9: return 1.47f; case 15: return 1.8f; case 16: return 1.8f; case 17: return 1.75f;
        case 35: return 1.85f; case 53: return 1.98f; default: return 1.6f;
    }
}
__device__ __forceinline__ float bond_of(int a, int b) {
    int lo = a < b ? a : b, hi = a < b ? b : a;
    switch (lo * 64 + hi) {
        case 6*64+6:   return 1.54f;
        case 6*64+7:   return 1.47f;
        case 6*64+8:   return 1.43f;
        case 6*64+16:  return 1.82f;
        case 6*64+9:   return 1.35f;
        case 6*64+17:  return 1.77f;
        case 1*64+6:   return 1.09f;
        case 7*64+7:   return 1.45f;
        case 7*64+8:   return 1.40f;
        case 1*64+7:   return 1.01f;
        case 8*64+8:   return 1.48f;
        case 1*64+8:   return 0.96f;
        case 16*64+16: return 2.05f;
        case 8*64+15:  return 1.63f;
        default:       return 1.5f;
    }
}

__device__ __forceinline__ float wave_reduce_sum(float x) {
    #pragma unroll
    for (int off = 32; off > 0; off >>= 1) x += __shfl_down(x, off);
    return x;  // valid in lane 0 of each wave
}

// Sense-reversing software grid barrier. Cross-XCD visibility via device-scope
// acquire/release atomics + __threadfence (pattern HW-validated in round 1).
// Requires all NB blocks co-resident (guaranteed: 512 blocks, 2/CU, 4KB LDS, low VGPR).
__device__ __forceinline__ void gbar(int* cnt, int* gen) {
    __syncthreads();
    if (threadIdx.x == 0) {
        __threadfence();  // flush this block's writes before signaling arrival
        int g = __hip_atomic_load(gen, __ATOMIC_RELAXED, __HIP_MEMORY_SCOPE_AGENT);
        int n = __hip_atomic_fetch_add(cnt, 1, __ATOMIC_ACQ_REL, __HIP_MEMORY_SCOPE_AGENT);
        if (n == NB - 1) {
            __hip_atomic_store(cnt, 0, __ATOMIC_RELAXED, __HIP_MEMORY_SCOPE_AGENT);
            __hip_atomic_store(gen, g + 1, __ATOMIC_RELEASE, __HIP_MEMORY_SCOPE_AGENT);
        } else {
            while (__hip_atomic_load(gen, __ATOMIC_ACQUIRE, __HIP_MEMORY_SCOPE_AGENT) == g) {
                __builtin_amdgcn_s_sleep(1);
            }
        }
        __threadfence();
    }
    __syncthreads();
}

// branchless steric pair: accumulates unscaled coeff-hat = t1/dist (scaled by 0.0025 at reduce)
__device__ __forceinline__ void steric_pair(const float4 p, const float4 q,
                                            float& cs, float& sx, float& sy, float& sz,
                                            float& ll) {
    float dx = p.x - q.x, dy = p.y - q.y, dz = p.z - q.z;
    float d2 = fmaf(dx, dx, fmaf(dy, dy, dz * dz));
    float md = p.w + q.w;
    float rinv = rsqrtf(fmaxf(d2, 1e-12f));
    float dist = d2 * rinv;                 // sqrt(d2); exactly 0 on the diagonal (d2==0)
    float t1 = md - dist;
    // d2 > 1e-12 excludes exactly the diagonal (min real pair dist ~0.04)
    bool ok = (t1 > 0.f) && (d2 > 1e-12f);
    float t1c = ok ? t1 : 0.f;
    ll = fmaf(t1c, t1c, ll);
    float co = t1c * rinv;
    cs += co;
    sx = fmaf(co, q.x, sx);
    sy = fmaf(co, q.y, sy);
    sz = fmaf(co, q.z, sz);
}

__global__ void __launch_bounds__(NT, 2)
k_fused(const float* __restrict__ pos, const int* __restrict__ row,
        const int* __restrict__ col, const int* __restrict__ types,
        int* __restrict__ deg, float* __restrict__ lossAcc, int* __restrict__ bar,
        float4* __restrict__ pos2, float* __restrict__ pos2f,
        float* __restrict__ pos1a, float* __restrict__ pos1,
        float* __restrict__ viol, float4* __restrict__ partial,
        float* __restrict__ out) {
    const int t = threadIdx.x;
    const int b = blockIdx.x;
    const int gid = b * NT + t;
    int* cnt = bar;
    int* gen = bar + 1;

    // ---- P1: out-degree histogram ----
    if (gid < NE) atomicAdd(&deg[row[gid]], 1);
    gbar(cnt, gen);

    // ---- P2: per-atom prep (viol, pos1a/pos1/pos2 init) + valence loss ----
    {
        float l0 = 0.f;
        if (gid < NA) {
            int z = types[gid];
            float v = fmaxf((float)deg[gid] - maxval_of(z), 0.f);
            viol[gid] = v;
            l0 = v * v;
            float x = pos[3*gid], y = pos[3*gid+1], zc = pos[3*gid+2];
            pos1a[3*gid] = x; pos1a[3*gid+1] = y; pos1a[3*gid+2] = zc;
            pos1[3*gid]  = x; pos1[3*gid+1]  = y; pos1[3*gid+2]  = zc;
            pos2[gid] = make_float4(x, y, zc, vdw_of(z) * 0.8f);
        }
        float part = wave_reduce_sum(l0);
        if ((t & 63) == 0 && part != 0.f) atomicAdd(&lossAcc[0], part);
    }
    gbar(cnt, gen);

    // ---- P3: valence push pass A (all neighbors from original pos) ----
    // Jacobi approximation of the sequential scan; per-row contribution exact to
    // first order (displacements ~1e-3 vs ~10 A distances; approx error ~3e-5).
    if (gid < NE) {
        int r = row[gid];
        float v = viol[r];
        int c = col[gid];
        if (v > 0.f && c != r) {
            float dx = pos[3*r]   - pos[3*c];
            float dy = pos[3*r+1] - pos[3*c+1];
            float dz = pos[3*r+2] - pos[3*c+2];
            float dist = sqrtf(dx*dx + dy*dy + dz*dz) + 1e-8f;
            float sc = v * 1e-3f / dist;
            atomicAdd(&pos1a[3*r],   dx * sc);
            atomicAdd(&pos1a[3*r+1], dy * sc);
            atomicAdd(&pos1a[3*r+2], dz * sc);
        }
    }
    gbar(cnt, gen);

    // ---- P4: valence push pass B (c<r reads pass-A result) -> pos1 and pos2 ----
    if (gid < NE) {
        int r = row[gid];
        float v = viol[r];
        int c = col[gid];
        if (v > 0.f && c != r) {
            float qx, qy, qz;
            if (c < r) { qx = pos1a[3*c]; qy = pos1a[3*c+1]; qz = pos1a[3*c+2]; }
            else       { qx = pos[3*c];   qy = pos[3*c+1];   qz = pos[3*c+2]; }
            float dx = pos[3*r]   - qx;
            float dy = pos[3*r+1] - qy;
            float dz = pos[3*r+2] - qz;
            float dist = sqrtf(dx*dx + dy*dy + dz*dz) + 1e-8f;
            float sc = v * 1e-3f / dist;
            float ax = dx * sc, ay = dy * sc, az = dz * sc;
            atomicAdd(&pos1[3*r],   ax);
            atomicAdd(&pos1[3*r+1], ay);
            atomicAdd(&pos1[3*r+2], az);
            atomicAdd(&pos2f[4*r],   ax);
            atomicAdd(&pos2f[4*r+1], ay);
            atomicAdd(&pos2f[4*r+2], az);
        }
    }
    gbar(cnt, gen);

    // ---- P5: bond-length correction (gather pos1, scatter into pos2) + loss ----
    {
        float l1 = 0.f;
        if (gid < NE) {
            int r = row[gid], c = col[gid];
            float bx = pos1[3*r]   - pos1[3*c];
            float by = pos1[3*r+1] - pos1[3*c+1];
            float bz = pos1[3*r+2] - pos1[3*c+2];
            float cur = sqrtf(bx*bx + by*by + bz*bz);
            float tgt = bond_of(types[r], types[c]);
            float diff = cur - tgt;
            l1 = diff * diff;
            float ratio = tgt / (cur + 1e-8f);
            ratio = fminf(fmaxf(ratio, 0.98f), 1.02f);
            float s = (ratio - 1.f) * 0.01f * 0.5f;
            atomicAdd(&pos2f[4*r],   bx * s);
            atomicAdd(&pos2f[4*r+1], by * s);
            atomicAdd(&pos2f[4*r+2], bz * s);
            atomicAdd(&pos2f[4*c],   -bx * s);
            atomicAdd(&pos2f[4*c+1], -by * s);
            atomicAdd(&pos2f[4*c+2], -bz * s);
        }
        float part = wave_reduce_sum(l1);
        if ((t & 63) == 0 && part != 0.f) atomicAdd(&lossAcc[1], part);
    }
    gbar(cnt, gen);

    // ---- P6: steric all-pairs tile -> non-atomic partial[y][i] (NO output atomics) ----
    {
        __shared__ float4 sm[JCHUNK];
        int yb = b >> 4;           // [0, 32) j-slice
        int ib = b & 15;           // [0, 16) i-block of 512 atoms
        int i0 = ib * 512 + t;
        int i1 = i0 + 256;
        float4 p0 = pos2[i0];
        float4 p1 = pos2[i1];
        sm[t] = pos2[yb * JCHUNK + t];
        __syncthreads();
        float cs0 = 0.f, sx0 = 0.f, sy0 = 0.f, sz0 = 0.f;
        float cs1 = 0.f, sx1 = 0.f, sy1 = 0.f, sz1 = 0.f;
        float ll = 0.f;
        #pragma unroll 8
        for (int jj = 0; jj < JCHUNK; jj++) {
            float4 q = sm[jj];
            steric_pair(p0, q, cs0, sx0, sy0, sz0, ll);
            steric_pair(p1, q, cs1, sx1, sy1, sz1, ll);
        }
        partial[yb * NA + i0] = make_float4(cs0, sx0, sy0, sz0);
        partial[yb * NA + i1] = make_float4(cs1, sx1, sy1, sz1);
        float part = wave_reduce_sum(ll);
        if ((t & 63) == 0 && part != 0.f) atomicAdd(&lossAcc[2], part);
    }
    gbar(cnt, gen);

    // ---- P7: reduce 32 slices/atom (16 lanes x 2 slices) + final output ----
    {
        int a = gid >> 4;          // atom [0, 8192)
        int s = gid & 15;          // slice-group within atom
        float4 u = partial[(2*s)     * NA + a];
        float4 w = partial[(2*s + 1) * NA + a];
        float cs = u.x + w.x, sx = u.y + w.y, sy = u.z + w.z, sz = u.w + w.w;
        #pragma unroll
        for (int off = 8; off > 0; off >>= 1) {
            cs += __shfl_down(cs, off, 16);
            sx += __shfl_down(sx, off, 16);
            sy += __shfl_down(sy, off, 16);
            sz += __shfl_down(sz, off, 16);
        }
        if (s == 0) {
            float4 p = pos2[a];
            float c = 1.f + cs * 0.0025f;
            out[3*a]   = p.x * c - sx * 0.0025f;
            out[3*a+1] = p.y * c - sy * 0.0025f;
            out[3*a+2] = p.z * c - sz * 0.0025f;
        }
        if (gid == 0) {
            float loss = lossAcc[0] + lossAcc[1] * (1.f / NE) + lossAcc[2] * 0.5f;
            out[3*NA] = loss * 0.1f;
        }
    }
}

extern "C" void kernel_launch(void* const* d_in, const int* in_sizes, int n_in,
                              void* d_out, int out_size, void* d_ws, size_t ws_size,
                              hipStream_t stream) {
    (void)in_sizes; (void)n_in; (void)out_size; (void)ws_size;
    const float* pos   = (const float*)d_in[0];
    const int*   eidx  = (const int*)d_in[1];
    const int*   types = (const int*)d_in[2];
    const int* row = eidx;
    const int* col = eidx + NE;

    int*   ws_i = (int*)d_ws;
    float* ws_f = (float*)d_ws;
    int*    deg     = ws_i + WS_DEG;
    float*  lossAcc = ws_f + WS_LOSS;
    int*    bar     = ws_i + WS_BAR;
    float4* pos2    = (float4*)(ws_f + WS_POS2);
    float*  pos2f   = ws_f + WS_POS2;
    float*  pos1a   = ws_f + WS_POS1A;
    float*  pos1    = ws_f + WS_POS1;
    float*  viol    = ws_f + WS_VIOL;
    float4* partial = (float4*)(ws_f + WS_PART);
    float*  out     = (float*)d_out;

    hipMemsetAsync(d_ws, 0, (size_t)WS_ZERO_END * 4, stream);
    k_fused<<<NB, NT, 0, stream>>>(pos, row, col, types, deg, lossAcc, bar,
                                   pos2, pos2f, pos1a, pos1, viol, partial, out);
}

// Round 5
// 135.885 us; speedup vs baseline: 5.0949x; 5.0949x over previous
//
#include <hip/hip_runtime.h>
#include <math.h>

#define NA 8192
#define NE 32768
#define NT 256
#define JSPLIT 32
#define JCHUNK (NA / JSPLIT)   /* 256 j-atoms per steric tile */
#define NIB 16                 /* i-blocks: NA/(NT*2), ITILE=2 */

// ---- workspace layout (4-byte element offsets) ----
#define WS_DEG      0                      // int NA
#define WS_LOSS     (WS_DEG + NA)          // f32 4  [0]=valence [1]=bond [2]=steric
#define WS_DA       (WS_LOSS + 4)          // f32 3NA  push delta
#define WS_DC       (WS_DA + 3*NA)         // f32 3NA  bond delta
#define WS_ZERO_END (WS_DC + 3*NA)         // zero [0, WS_ZERO_END) = 224 KB
#define WS_PART     WS_ZERO_END            // float4 JSPLIT*NA = 4 MB (57348*4 % 16 == 0)
// total ws = (57348 + 4*32*8192)*4 B ~= 4.42 MB (round 4 proved ws_size >= 4.6 MB)

// ---- chemistry tables (types present: {1,6,7,8,9,15,16,17}) ----
__device__ __forceinline__ float maxval_of(int z) {
    switch (z) {
        case 1: return 1.f; case 6: return 4.f; case 7: return 3.f; case 8: return 2.f;
        case 9: return 1.f; case 15: return 5.f; case 16: return 6.f; case 17: return 1.f;
        case 35: return 1.f; case 53: return 1.f; default: return 4.f;
    }
}
__device__ __forceinline__ float vdw_of(int z) {
    switch (z) {
        case 1: return 1.2f; case 6: return 1.7f; case 7: return 1.55f; case 8: return 1.52f;
        case 9: return 1.47f; case 15: return 1.8f; case 16: return 1.8f; case 17: return 1.75f;
        case 35: return 1.85f; case 53: return 1.98f; default: return 1.6f;
    }
}
__device__ __forceinline__ float bond_of(int a, int b) {
    int lo = a < b ? a : b, hi = a < b ? b : a;
    switch (lo * 64 + hi) {
        case 6*64+6:   return 1.54f;
        case 6*64+7:   return 1.47f;
        case 6*64+8:   return 1.43f;
        case 6*64+16:  return 1.82f;
        case 6*64+9:   return 1.35f;
        case 6*64+17:  return 1.77f;
        case 1*64+6:   return 1.09f;
        case 7*64+7:   return 1.45f;
        case 7*64+8:   return 1.40f;
        case 1*64+7:   return 1.01f;
        case 8*64+8:   return 1.48f;
        case 1*64+8:   return 0.96f;
        case 16*64+16: return 2.05f;
        case 8*64+15:  return 1.63f;
        default:       return 1.5f;
    }
}
__device__ __forceinline__ float viol_of(int d, int z) {
    return fmaxf((float)d - maxval_of(z), 0.f);
}

__device__ __forceinline__ float wave_reduce_sum(float x) {
    #pragma unroll
    for (int off = 32; off > 0; off >>= 1) x += __shfl_down(x, off);
    return x;  // valid in lane 0 of each wave
}

// ---- 1. out-degree histogram ----
__global__ void k_degree(const int* __restrict__ row, int* __restrict__ deg) {
    int e = blockIdx.x * NT + threadIdx.x;
    if (e < NE) atomicAdd(&deg[row[e]], 1);
}

// ---- 2. valence push (single Jacobi pass; vs sequential scan error ~1e-5) ----
__global__ void k_push(const int* __restrict__ row, const int* __restrict__ col,
                       const int* __restrict__ types, const int* __restrict__ deg,
                       const float* __restrict__ pos, float* __restrict__ dA) {
    int e = blockIdx.x * NT + threadIdx.x;
    if (e >= NE) return;
    int r = row[e];
    float v = viol_of(deg[r], types[r]);
    int c = col[e];
    if (v <= 0.f || c == r) return;           // self-edge: zero displacement
    float dx = pos[3*r]   - pos[3*c];
    float dy = pos[3*r+1] - pos[3*c+1];
    float dz = pos[3*r+2] - pos[3*c+2];
    float dist = sqrtf(dx*dx + dy*dy + dz*dz) + 1e-8f;
    float sc = v * 1e-3f / dist;
    atomicAdd(&dA[3*r],   dx * sc);
    atomicAdd(&dA[3*r+1], dy * sc);
    atomicAdd(&dA[3*r+2], dz * sc);
}

// ---- 3. bond correction (gather pos+dA, scatter dC) + valence & bond losses ----
__global__ void k_bond(const int* __restrict__ row, const int* __restrict__ col,
                       const int* __restrict__ types, const int* __restrict__ deg,
                       const float* __restrict__ pos, const float* __restrict__ dA,
                       float* __restrict__ dC, float* __restrict__ lossAcc) {
    int e = blockIdx.x * NT + threadIdx.x;
    float l1 = 0.f, l0 = 0.f;
    if (e < NE) {
        int r = row[e], c = col[e];
        float bx = (pos[3*r]   + dA[3*r])   - (pos[3*c]   + dA[3*c]);
        float by = (pos[3*r+1] + dA[3*r+1]) - (pos[3*c+1] + dA[3*c+1]);
        float bz = (pos[3*r+2] + dA[3*r+2]) - (pos[3*c+2] + dA[3*c+2]);
        float cur = sqrtf(bx*bx + by*by + bz*bz);
        float tgt = bond_of(types[r], types[c]);
        float diff = cur - tgt;
        l1 = diff * diff;
        float ratio = tgt / (cur + 1e-8f);
        ratio = fminf(fmaxf(ratio, 0.98f), 1.02f);
        float s = (ratio - 1.f) * 0.01f * 0.5f;
        atomicAdd(&dC[3*r],   bx * s);
        atomicAdd(&dC[3*r+1], by * s);
        atomicAdd(&dC[3*r+2], bz * s);
        atomicAdd(&dC[3*c],   -bx * s);
        atomicAdd(&dC[3*c+1], -by * s);
        atomicAdd(&dC[3*c+2], -bz * s);
    }
    if (e < NA) {                              // fold valence loss into this launch
        float v = viol_of(deg[e], types[e]);
        l0 = v * v;
    }
    float p1 = wave_reduce_sum(l1);
    float p0 = wave_reduce_sum(l0);
    if ((threadIdx.x & 63) == 0) {
        if (p1 != 0.f) atomicAdd(&lossAcc[1], p1);
        if (p0 != 0.f) atomicAdd(&lossAcc[0], p0);
    }
}

// branchless steric pair: accumulates coeff-hat = t1/dist (x0.0025 applied at reduce)
__device__ __forceinline__ void steric_pair(const float4 p, const float4 q,
                                            float& cs, float& sx, float& sy, float& sz,
                                            float& ll) {
    float dx = p.x - q.x, dy = p.y - q.y, dz = p.z - q.z;
    float d2 = fmaf(dx, dx, fmaf(dy, dy, dz * dz));
    float md = p.w + q.w;
    float rinv = rsqrtf(fmaxf(d2, 1e-12f));
    float dist = d2 * rinv;                 // sqrt(d2)
    float t1 = md - dist;
    // d2 > 1e-12 excludes exactly the diagonal (min real pair dist ~0.04)
    bool ok = (t1 > 0.f) && (d2 > 1e-12f);
    float t1c = ok ? t1 : 0.f;
    ll = fmaf(t1c, t1c, ll);
    float co = t1c * rinv;
    cs += co;
    sx = fmaf(co, q.x, sx);
    sy = fmaf(co, q.y, sy);
    sz = fmaf(co, q.z, sz);
}

// ---- 4. steric all-pairs -> non-atomic partial[y][a]; pos2 built inline ----
__global__ void __launch_bounds__(NT)
k_steric(const float* __restrict__ pos, const float* __restrict__ dA,
         const float* __restrict__ dC, const int* __restrict__ types,
         float4* __restrict__ partial, float* __restrict__ lossAcc) {
    __shared__ float4 sm[JCHUNK];
    const int t = threadIdx.x;
    const int b = blockIdx.x;
    const int yb = b >> 4;                 // [0,32) j-slice
    const int ib = b & 15;                 // [0,16) i-block of 512 atoms
    // stage j-tile: pos2[j] = pos + dA + dC, w = vdw*0.8
    int j = yb * JCHUNK + t;
    sm[t] = make_float4(pos[3*j]   + dA[3*j]   + dC[3*j],
                        pos[3*j+1] + dA[3*j+1] + dC[3*j+1],
                        pos[3*j+2] + dA[3*j+2] + dC[3*j+2],
                        vdw_of(types[j]) * 0.8f);
    int i0 = ib * 512 + t;
    int i1 = i0 + 256;
    float4 p0 = make_float4(pos[3*i0]   + dA[3*i0]   + dC[3*i0],
                            pos[3*i0+1] + dA[3*i0+1] + dC[3*i0+1],
                            pos[3*i0+2] + dA[3*i0+2] + dC[3*i0+2],
                            vdw_of(types[i0]) * 0.8f);
    float4 p1 = make_float4(pos[3*i1]   + dA[3*i1]   + dC[3*i1],
                            pos[3*i1+1] + dA[3*i1+1] + dC[3*i1+1],
                            pos[3*i1+2] + dA[3*i1+2] + dC[3*i1+2],
                            vdw_of(types[i1]) * 0.8f);
    __syncthreads();
    float cs0 = 0.f, sx0 = 0.f, sy0 = 0.f, sz0 = 0.f;
    float cs1 = 0.f, sx1 = 0.f, sy1 = 0.f, sz1 = 0.f;
    float ll = 0.f;
    #pragma unroll 8
    for (int jj = 0; jj < JCHUNK; jj++) {
        float4 q = sm[jj];
        steric_pair(p0, q, cs0, sx0, sy0, sz0, ll);
        steric_pair(p1, q, cs1, sx1, sy1, sz1, ll);
    }
    partial[yb * NA + i0] = make_float4(cs0, sx0, sy0, sz0);
    partial[yb * NA + i1] = make_float4(cs1, sx1, sy1, sz1);
    float part = wave_reduce_sum(ll);
    if ((t & 63) == 0 && part != 0.f) atomicAdd(&lossAcc[2], part);
}

// ---- 5. reduce 32 slices/atom (coalesced) + final output + loss scalar ----
__global__ void k_reduce(const float* __restrict__ pos, const float* __restrict__ dA,
                         const float* __restrict__ dC, const float4* __restrict__ partial,
                         const float* __restrict__ lossAcc, float* __restrict__ out) {
    int a = blockIdx.x * NT + threadIdx.x;   // 32 blocks x 256 = NA
    float cs = 0.f, sx = 0.f, sy = 0.f, sz = 0.f;
    #pragma unroll 8
    for (int y = 0; y < JSPLIT; y++) {
        float4 u = partial[y * NA + a];      // coalesced: consecutive a per lane
        cs += u.x; sx += u.y; sy += u.z; sz += u.w;
    }
    float px = pos[3*a]   + dA[3*a]   + dC[3*a];
    float py = pos[3*a+1] + dA[3*a+1] + dC[3*a+1];
    float pz = pos[3*a+2] + dA[3*a+2] + dC[3*a+2];
    float c = 1.f + cs * 0.0025f;
    out[3*a]   = px * c - sx * 0.0025f;
    out[3*a+1] = py * c - sy * 0.0025f;
    out[3*a+2] = pz * c - sz * 0.0025f;
    if (a == 0) {
        float loss = lossAcc[0] + lossAcc[1] * (1.f / NE) + lossAcc[2] * 0.5f;
        out[3*NA] = loss * 0.1f;
    }
}

extern "C" void kernel_launch(void* const* d_in, const int* in_sizes, int n_in,
                              void* d_out, int out_size, void* d_ws, size_t ws_size,
                              hipStream_t stream) {
    (void)in_sizes; (void)n_in; (void)out_size; (void)ws_size;
    const float* pos   = (const float*)d_in[0];
    const int*   eidx  = (const int*)d_in[1];
    const int*   types = (const int*)d_in[2];
    const int* row = eidx;
    const int* col = eidx + NE;

    int*   ws_i = (int*)d_ws;
    float* ws_f = (float*)d_ws;
    int*    deg     = ws_i + WS_DEG;
    float*  lossAcc = ws_f + WS_LOSS;
    float*  dA      = ws_f + WS_DA;
    float*  dC      = ws_f + WS_DC;
    float4* partial = (float4*)(ws_f + WS_PART);
    float*  out     = (float*)d_out;

    hipMemsetAsync(d_ws, 0, (size_t)WS_ZERO_END * 4, stream);
    k_degree<<<NE/NT, NT, 0, stream>>>(row, deg);
    k_push  <<<NE/NT, NT, 0, stream>>>(row, col, types, deg, pos, dA);
    k_bond  <<<NE/NT, NT, 0, stream>>>(row, col, types, deg, pos, dA, dC, lossAcc);
    k_steric<<<JSPLIT*NIB, NT, 0, stream>>>(pos, dA, dC, types, partial, lossAcc);
    k_reduce<<<NA/NT, NT, 0, stream>>>(pos, dA, dC, partial, lossAcc, out);
}